// Round 1
// baseline (534.819 us; speedup 1.0000x reference)
//
#include <hip/hip_runtime.h>
#include <stdint.h>

#define NEGC (-1.0e9f)

typedef __attribute__((ext_vector_type(8))) short bf16x8;
typedef __attribute__((ext_vector_type(4))) float f32x4;

__device__ __forceinline__ unsigned short f2bf(float f) {
    union { float f; unsigned int u; } v; v.f = f;
    unsigned int r = v.u + 0x7fffu + ((v.u >> 16) & 1u);
    return (unsigned short)(r >> 16);
}
__device__ __forceinline__ float bf2f(unsigned short h) {
    union { float f; unsigned int u; } v; v.u = ((unsigned int)h) << 16;
    return v.f;
}

// ---- LDS layout (bytes) for kernel 1 ----
// Phase A: S | QH | QL | KH | KL | M2F
// Phase B: S | A2(bf16, overlays QH/QL/KH) | M2F
// Phase C: A2 | T(overlays tail of KH/KL region)
#define S_STRIDE 516
#define Q_STRIDE 136
#define A2_STRIDE 520
#define T_STRIDE 72
#define OFF_S   0
#define OFF_QH  66048
#define OFF_QL  74752
#define OFF_KH  83456
#define OFF_KL  100864
#define OFF_M2  118272
#define OFF_A2  66048
#define OFF_T   99328
#define SMEM_SZ 120320

__global__ __launch_bounds__(256) void bidir_main(
    const float* __restrict__ seq1, const float* __restrict__ seq2,
    const int* __restrict__ m1, const int* __restrict__ m2,
    float* __restrict__ out0, float* __restrict__ a2out,
    float* __restrict__ a1log)
{
    __shared__ __align__(16) char smem[SMEM_SZ];
    float*          Sl  = (float*)(smem + OFF_S);
    unsigned short* QH  = (unsigned short*)(smem + OFF_QH);
    unsigned short* QL  = (unsigned short*)(smem + OFF_QL);
    unsigned short* KH  = (unsigned short*)(smem + OFF_KH);
    unsigned short* KL  = (unsigned short*)(smem + OFF_KL);
    unsigned short* A2  = (unsigned short*)(smem + OFF_A2);
    unsigned short* Tt  = (unsigned short*)(smem + OFF_T);
    float*          M2F = (float*)(smem + OFF_M2);

    const int t  = threadIdx.x;
    const int b  = blockIdx.x >> 6;      // 64 n-tiles per batch
    const int nt = blockIdx.x & 63;
    const int n0 = nt * 32;
    const int lane = t & 63;
    const int w  = t >> 6;
    const int wr = w >> 1, wc = w & 1;   // 2x2 wave grid
    const int g  = lane >> 4, fr = lane & 15;

    // m2 mask as float
    for (int i = t; i < 512; i += 256) M2F[i] = (float)m2[b * 512 + i];

    // ---- load seq1 tile [32][128] -> QH/QL (split bf16) ----
#pragma unroll
    for (int p = 0; p < 4; ++p) {
        int f4 = p * 256 + t;
        int row = f4 >> 5, c4 = f4 & 31;
        const float4 v = ((const float4*)(seq1 + ((size_t)(b * 2048 + n0 + row)) * 128))[c4];
        float vs[4] = {v.x, v.y, v.z, v.w};
        unsigned short h[4], l[4];
#pragma unroll
        for (int i = 0; i < 4; ++i) { h[i] = f2bf(vs[i]); l[i] = f2bf(vs[i] - bf2f(h[i])); }
        ushort4 uh{h[0], h[1], h[2], h[3]};
        ushort4 ul{l[0], l[1], l[2], l[3]};
        *(ushort4*)(&QH[row * Q_STRIDE + c4 * 4]) = uh;
        *(ushort4*)(&QL[row * Q_STRIDE + c4 * 4]) = ul;
    }
    __syncthreads();

    // A-fragments (rows wr*16+fr, 8 contiguous k per lane-group)
    bf16x8 ah[4], al[4];
#pragma unroll
    for (int ks = 0; ks < 4; ++ks) {
        ah[ks] = *(const bf16x8*)(&QH[(wr * 16 + fr) * Q_STRIDE + ks * 32 + g * 8]);
        al[ks] = *(const bf16x8*)(&QL[(wr * 16 + fr) * Q_STRIDE + ks * 32 + g * 8]);
    }

    // ---- Phase A: S = seq1 . seq2^T via split-bf16 (hi*hi + hi*lo + lo*hi) ----
    for (int mt = 0; mt < 8; ++mt) {
#pragma unroll
        for (int p = 0; p < 8; ++p) {
            int f4 = p * 256 + t;
            int row = f4 >> 5, c4 = f4 & 31;
            const float4 v = ((const float4*)(seq2 + ((size_t)(b * 512 + mt * 64 + row)) * 128))[c4];
            float vs[4] = {v.x, v.y, v.z, v.w};
            unsigned short h[4], l[4];
#pragma unroll
            for (int i = 0; i < 4; ++i) { h[i] = f2bf(vs[i]); l[i] = f2bf(vs[i] - bf2f(h[i])); }
            ushort4 uh{h[0], h[1], h[2], h[3]};
            ushort4 ul{l[0], l[1], l[2], l[3]};
            *(ushort4*)(&KH[row * Q_STRIDE + c4 * 4]) = uh;
            *(ushort4*)(&KL[row * Q_STRIDE + c4 * 4]) = ul;
        }
        __syncthreads();

        f32x4 acc0 = {0.f, 0.f, 0.f, 0.f};
        f32x4 acc1 = {0.f, 0.f, 0.f, 0.f};
#pragma unroll
        for (int ks = 0; ks < 4; ++ks) {
            bf16x8 bh0 = *(const bf16x8*)(&KH[(wc * 32 + fr) * Q_STRIDE + ks * 32 + g * 8]);
            bf16x8 bl0 = *(const bf16x8*)(&KL[(wc * 32 + fr) * Q_STRIDE + ks * 32 + g * 8]);
            bf16x8 bh1 = *(const bf16x8*)(&KH[(wc * 32 + 16 + fr) * Q_STRIDE + ks * 32 + g * 8]);
            bf16x8 bl1 = *(const bf16x8*)(&KL[(wc * 32 + 16 + fr) * Q_STRIDE + ks * 32 + g * 8]);
            acc0 = __builtin_amdgcn_mfma_f32_16x16x32_bf16(al[ks], bh0, acc0, 0, 0, 0);
            acc0 = __builtin_amdgcn_mfma_f32_16x16x32_bf16(ah[ks], bl0, acc0, 0, 0, 0);
            acc0 = __builtin_amdgcn_mfma_f32_16x16x32_bf16(ah[ks], bh0, acc0, 0, 0, 0);
            acc1 = __builtin_amdgcn_mfma_f32_16x16x32_bf16(al[ks], bh1, acc1, 0, 0, 0);
            acc1 = __builtin_amdgcn_mfma_f32_16x16x32_bf16(ah[ks], bl1, acc1, 0, 0, 0);
            acc1 = __builtin_amdgcn_mfma_f32_16x16x32_bf16(ah[ks], bh1, acc1, 0, 0, 0);
        }
#pragma unroll
        for (int reg = 0; reg < 4; ++reg) {
            int row = wr * 16 + g * 4 + reg;
            Sl[row * S_STRIDE + mt * 64 + wc * 32 + fr]      = acc0[reg];
            Sl[row * S_STRIDE + mt * 64 + wc * 32 + 16 + fr] = acc1[reg];
        }
        __syncthreads();
    }

    // ---- Phase B: masked softmax rows (f32), write a2 (global f32 + LDS bf16), a1 logits ----
    {
        const int r = t >> 3, u = t & 7;
        float4* S4row = (float4*)(&Sl[r * S_STRIDE]);

        float rmax = NEGC;
#pragma unroll 4
        for (int j = 0; j < 16; ++j) {
            int f4 = u + 8 * j;
            float4 sv = S4row[f4];
            float vs[4] = {sv.x, sv.y, sv.z, sv.w};
#pragma unroll
            for (int i = 0; i < 4; ++i) {
                float mm = M2F[f4 * 4 + i];
                rmax = fmaxf(rmax, (mm > 0.5f) ? vs[i] : NEGC);
            }
        }
        rmax = fmaxf(rmax, __shfl_xor(rmax, 1));
        rmax = fmaxf(rmax, __shfl_xor(rmax, 2));
        rmax = fmaxf(rmax, __shfl_xor(rmax, 4));

        float sum = 0.f;
#pragma unroll 4
        for (int j = 0; j < 16; ++j) {
            int f4 = u + 8 * j;
            float4 sv = S4row[f4];
            float vs[4] = {sv.x, sv.y, sv.z, sv.w};
            float es[4];
#pragma unroll
            for (int i = 0; i < 4; ++i) {
                float mm = M2F[f4 * 4 + i];
                es[i] = __expf(vs[i] + (1.0f - mm) * NEGC - rmax);
                sum += es[i];
            }
            float4 ev{es[0], es[1], es[2], es[3]};
            S4row[f4] = ev;
        }
        sum += __shfl_xor(sum, 1);
        sum += __shfl_xor(sum, 2);
        sum += __shfl_xor(sum, 4);
        float rinv = 1.0f / sum;

        float4* a2row = (float4*)(a2out + ((size_t)(b * 2048 + n0 + r)) * 512);
#pragma unroll 4
        for (int j = 0; j < 16; ++j) {
            int f4 = u + 8 * j;
            float4 ev = S4row[f4];
            float4 av{ev.x * rinv, ev.y * rinv, ev.z * rinv, ev.w * rinv};
            a2row[f4] = av;
            ushort4 ab{f2bf(av.x), f2bf(av.y), f2bf(av.z), f2bf(av.w)};
            *(ushort4*)(&A2[r * A2_STRIDE + f4 * 4]) = ab;
        }
        if (u == 0) {
            float m1v = (float)m1[b * 2048 + n0 + r];
            a1log[b * 2048 + n0 + r] = rmax + (1.0f - m1v) * NEGC;
        }
    }
    __syncthreads();

    // ---- Phase C: out0 = a2 . seq2 (plain bf16 MFMA, seq2 transposed per-tile in LDS) ----
    f32x4 oacc[4];
#pragma unroll
    for (int c = 0; c < 4; ++c) oacc[c] = (f32x4){0.f, 0.f, 0.f, 0.f};

    for (int mt = 0; mt < 8; ++mt) {
#pragma unroll
        for (int p = 0; p < 8; ++p) {
            int f4 = p * 256 + t;
            int mrow = f4 >> 5, d4 = f4 & 31;
            const float4 v = ((const float4*)(seq2 + ((size_t)(b * 512 + mt * 64 + mrow)) * 128))[d4];
            float vs[4] = {v.x, v.y, v.z, v.w};
#pragma unroll
            for (int i = 0; i < 4; ++i) Tt[(d4 * 4 + i) * T_STRIDE + mrow] = f2bf(vs[i]);
        }
        __syncthreads();
#pragma unroll
        for (int ks = 0; ks < 2; ++ks) {
            bf16x8 av = *(const bf16x8*)(&A2[(wr * 16 + fr) * A2_STRIDE + mt * 64 + ks * 32 + g * 8]);
#pragma unroll
            for (int c = 0; c < 4; ++c) {
                bf16x8 bv = *(const bf16x8*)(&Tt[(wc * 64 + c * 16 + fr) * T_STRIDE + ks * 32 + g * 8]);
                oacc[c] = __builtin_amdgcn_mfma_f32_16x16x32_bf16(av, bv, oacc[c], 0, 0, 0);
            }
        }
        __syncthreads();
    }

#pragma unroll
    for (int c = 0; c < 4; ++c)
#pragma unroll
        for (int reg = 0; reg < 4; ++reg) {
            int row = wr * 16 + g * 4 + reg;
            int col = wc * 64 + c * 16 + fr;
            out0[((size_t)(b * 2048 + n0 + row)) * 128 + col] = oacc[c][reg];
        }
}

// ---- kernel 2: a1 softmax over n + seq2_seq1_attention GEMV ----
__global__ __launch_bounds__(256) void bidir_q2c(
    const float* __restrict__ seq1, float* __restrict__ a1slot,
    float* __restrict__ out2)
{
    __shared__ float a1buf[2048];
    __shared__ float wred[4];
    __shared__ float red2[2][128];

    const int b = blockIdx.x, t = threadIdx.x, lane = t & 63, w = t >> 6;

    const float4* Lp = (const float4*)(a1slot + (size_t)b * 2048);
    float4 La = Lp[t * 2], Lb = Lp[t * 2 + 1];
    float l[8] = {La.x, La.y, La.z, La.w, Lb.x, Lb.y, Lb.z, Lb.w};

    float lmax = l[0];
#pragma unroll
    for (int j = 1; j < 8; ++j) lmax = fmaxf(lmax, l[j]);
#pragma unroll
    for (int off = 1; off < 64; off <<= 1) lmax = fmaxf(lmax, __shfl_xor(lmax, off));
    if (lane == 0) wred[w] = lmax;
    __syncthreads();
    float bmax = fmaxf(fmaxf(wred[0], wred[1]), fmaxf(wred[2], wred[3]));

    float e[8]; float s = 0.f;
#pragma unroll
    for (int j = 0; j < 8; ++j) { e[j] = __expf(l[j] - bmax); s += e[j]; }
#pragma unroll
    for (int off = 1; off < 64; off <<= 1) s += __shfl_xor(s, off);
    __syncthreads();
    if (lane == 0) wred[w] = s;
    __syncthreads();
    float bs = wred[0] + wred[1] + wred[2] + wred[3];
    float inv = 1.0f / bs;

    float4 o1{e[0] * inv, e[1] * inv, e[2] * inv, e[3] * inv};
    float4 o2v{e[4] * inv, e[5] * inv, e[6] * inv, e[7] * inv};
    ((float4*)(a1slot + (size_t)b * 2048))[t * 2] = o1;
    ((float4*)(a1slot + (size_t)b * 2048))[t * 2 + 1] = o2v;
#pragma unroll
    for (int j = 0; j < 8; ++j) a1buf[t * 8 + j] = e[j] * inv;
    __syncthreads();

    const int d = t & 127, gg = t >> 7;
    float acc = 0.f;
    const float* s1p = seq1 + (size_t)b * 2048 * 128 + d;
    for (int n = gg; n < 2048; n += 2) acc += a1buf[n] * s1p[(size_t)n * 128];
    red2[gg][d] = acc;
    __syncthreads();
    if (t < 128) out2[b * 128 + t] = red2[0][t] + red2[1][t];
}

extern "C" void kernel_launch(void* const* d_in, const int* in_sizes, int n_in,
                              void* d_out, int out_size, void* d_ws, size_t ws_size,
                              hipStream_t stream) {
    const float* seq1 = (const float*)d_in[0];
    const float* seq2 = (const float*)d_in[1];
    const int*   m1   = (const int*)d_in[2];
    const int*   m2   = (const int*)d_in[3];

    float* out  = (float*)d_out;
    float* out0 = out;                 // [32,2048,128] seq1_seq2_attention
    float* a2o  = out + 8388608;       // [32,2048,512] a2
    float* o2   = out + 41943040;      // [32,128]      seq2_seq1_attention
    float* a1o  = out + 41947136;      // [32,2048]     a1 (kernel1 stores logits, kernel2 finalizes)

    bidir_main<<<dim3(2048), dim3(256), 0, stream>>>(seq1, seq2, m1, m2, out0, a2o, a1o);
    bidir_q2c<<<dim3(32), dim3(256), 0, stream>>>(seq1, a1o, o2);
}

// Round 3
// 95.093 us; speedup vs baseline: 5.6242x; 5.6242x over previous
//
#include <hip/hip_runtime.h>
#include <stdint.h>

#define NEGC (-1.0e9f)

typedef __attribute__((ext_vector_type(8))) short bf16x8;
typedef __attribute__((ext_vector_type(4))) float f32x4;

// precomputed seq2 forms: hi/lo split bf16 [b][m][d], and transposed bf16 [b][d][m]
__device__ __align__(16) unsigned short g_S2H[32u * 512u * 128u];
__device__ __align__(16) unsigned short g_S2L[32u * 512u * 128u];
__device__ __align__(16) unsigned short g_VT[32u * 128u * 512u];
__device__ float g_part[32 * 8 * 128];

__device__ __forceinline__ unsigned short f2bf(float f) {
    union { float f; unsigned int u; } v; v.f = f;
    unsigned int r = v.u + 0x7fffu + ((v.u >> 16) & 1u);
    return (unsigned short)(r >> 16);
}
__device__ __forceinline__ float bf2f(unsigned short h) {
    union { float f; unsigned int u; } v; v.u = ((unsigned int)h) << 16;
    return v.f;
}

__device__ __forceinline__ void gl_lds16(const void* g, void* l) {
    __builtin_amdgcn_global_load_lds(
        (const __attribute__((address_space(1))) unsigned int*)g,
        (__attribute__((address_space(3))) unsigned int*)l, 16, 0, 0);
}

// ---- prep: seq2 -> bf16 hi/lo split + transposed bf16 ----
__global__ __launch_bounds__(256) void k_prep(const float* __restrict__ seq2) {
    const int b = blockIdx.x >> 1, h = blockIdx.x & 1, t = threadIdx.x;
    // convert 256 m-rows
    const float4* src = (const float4*)(seq2 + (size_t)(b * 512 + h * 256) * 128);
    ushort4* dh = (ushort4*)(g_S2H + (size_t)(b * 512 + h * 256) * 128);
    ushort4* dl = (ushort4*)(g_S2L + (size_t)(b * 512 + h * 256) * 128);
#pragma unroll 4
    for (int p = 0; p < 32; ++p) {
        float4 v = src[p * 256 + t];
        float vs[4] = {v.x, v.y, v.z, v.w};
        unsigned short hh[4], ll[4];
#pragma unroll
        for (int i = 0; i < 4; ++i) { hh[i] = f2bf(vs[i]); ll[i] = f2bf(vs[i] - bf2f(hh[i])); }
        ushort4 uh{hh[0], hh[1], hh[2], hh[3]};
        ushort4 ul{ll[0], ll[1], ll[2], ll[3]};
        dh[p * 256 + t] = uh;
        dl[p * 256 + t] = ul;
    }
    // transpose: VT[b][d][m] = bf16(seq2[b][m][d]); this block: d in [h*64, h*64+64)
    const int d = h * 64 + (t & 63), mq = t >> 6;
#pragma unroll 2
    for (int j = 0; j < 16; ++j) {
        int mb = (mq * 16 + j) * 8;
        unsigned short pk[8];
#pragma unroll
        for (int i = 0; i < 8; ++i)
            pk[i] = f2bf(seq2[(size_t)(b * 512 + mb + i) * 128 + d]);
        ushort4 p0{pk[0], pk[1], pk[2], pk[3]};
        ushort4 p1{pk[4], pk[5], pk[6], pk[7]};
        *(ushort4*)(g_VT + (size_t)(b * 128 + d) * 512 + mb) = p0;
        *(ushort4*)(g_VT + (size_t)(b * 128 + d) * 512 + mb + 4) = p1;
    }
}

// ---- LDS layout (bytes) ----
// phase A: QH @0 (8K) | QL @8192 (8K) | KH[2] @16384 (16K) | KL[2] @32768 (16K)
// phase B/C: A2 bf16 [32][512] @0 (32K) | T bf16 [128][64] @32768 (16K)
// M2 u8 @49152 (512B) | REDm [2][32] f32 @49664 | REDs [2][32] f32 @49920
#define KBASE 16384
#define TBASE 32768
#define M2OFF 49152
#define REDOFF 49664
#define LDS_TOTAL 50176

__global__ __launch_bounds__(256, 3) void bidir_main(
    const float* __restrict__ seq1,
    const int* __restrict__ m1, const int* __restrict__ m2,
    float* __restrict__ out0, float* __restrict__ a2out,
    float* __restrict__ a1log)
{
    __shared__ __align__(16) char smem[LDS_TOTAL];

    const int t = threadIdx.x, lane = t & 63, w = t >> 6;
    const int wr = w >> 1, wc = w & 1, q = lane >> 4, fr = lane & 15;
    const int orig = blockIdx.x;
    const int swzb = (orig & 7) * 256 + (orig >> 3);   // XCD-contiguous
    const int b = swzb >> 6, n0 = (swzb & 63) << 5;

    unsigned char* M2u8 = (unsigned char*)(smem + M2OFF);
    float* REDm = (float*)(smem + REDOFF);
    float* REDs = (float*)(smem + REDOFF + 256);

    // stage m2 mask as u8
    if (t < 128) {
        int4 v = ((const int4*)(m2 + b * 512))[t];
        uchar4 u{(unsigned char)v.x, (unsigned char)v.y, (unsigned char)v.z, (unsigned char)v.w};
        *(uchar4*)(M2u8 + t * 4) = u;
    }
    // stage Q tile (split bf16, swizzled)
    {
        const float4* s1p = (const float4*)(seq1 + (size_t)(b * 2048 + n0) * 128);
#pragma unroll
        for (int p = 0; p < 4; ++p) {
            int idx = p * 256 + t;
            int row = idx >> 5, c4 = idx & 31;
            float4 v = s1p[idx];
            float vs[4] = {v.x, v.y, v.z, v.w};
            unsigned short hh[4], ll[4];
#pragma unroll
            for (int i = 0; i < 4; ++i) { hh[i] = f2bf(vs[i]); ll[i] = f2bf(vs[i] - bf2f(hh[i])); }
            ushort4 uh{hh[0], hh[1], hh[2], hh[3]};
            ushort4 ul{ll[0], ll[1], ll[2], ll[3]};
            int off = (row * 256 + c4 * 8) ^ ((row & 7) << 4);
            *(ushort4*)(smem + off) = uh;
            *(ushort4*)(smem + 8192 + off) = ul;
        }
    }
    __syncthreads();

    // A fragments (Q rows wr*16+fr)
    bf16x8 ah[4], al[4];
    {
        int row = wr * 16 + fr;
        int sw = (row & 7) << 4;
#pragma unroll
        for (int ks = 0; ks < 4; ++ks) {
            int off = (row * 256 + ks * 64 + q * 16) ^ sw;
            ah[ks] = *(const bf16x8*)(smem + off);
            al[ks] = *(const bf16x8*)(smem + 8192 + off);
        }
    }

    f32x4 acc[8][2];
#pragma unroll
    for (int i = 0; i < 8; ++i) {
        acc[i][0] = (f32x4){0.f, 0.f, 0.f, 0.f};
        acc[i][1] = (f32x4){0.f, 0.f, 0.f, 0.f};
    }

    // ---- phase A: S = seq1 . seq2^T (split bf16, 3 MFMA) ----
    // wave w stages m-rows (w&1)*256 + mt*32 + [0,32): w<2 -> hi, w>=2 -> lo.
    // => acc[mt][s] for wave-col wc holds TRUE m = wc*256 + mt*32 + s*16 + fr.
#pragma unroll
    for (int mt = 0; mt < 8; ++mt) {
        {
            const unsigned short* sb = (w < 2) ? g_S2H : g_S2L;
            const char* srcb = (const char*)(sb + (size_t)(b * 512 + (w & 1) * 256 + mt * 32) * 128);
            char* dstb = smem + KBASE + w * 8192;
#pragma unroll
            for (int i = 0; i < 8; ++i) {
                int r = i * 4 + q;
                int so = r * 256 + ((fr * 16) ^ ((r & 7) << 4));
                gl_lds16(srcb + so, dstb + i * 1024);
            }
        }
        __syncthreads();
        {
            const char* KH = smem + KBASE + wc * 8192;
            const char* KL = smem + KBASE + 16384 + wc * 8192;
#pragma unroll
            for (int s = 0; s < 2; ++s) {
                int rrow = s * 16 + fr;
                int sw = (fr & 7) << 4;
#pragma unroll
                for (int ks = 0; ks < 4; ++ks) {
                    int off = (rrow * 256 + ks * 64 + q * 16) ^ sw;
                    bf16x8 bh = *(const bf16x8*)(KH + off);
                    bf16x8 bl = *(const bf16x8*)(KL + off);
                    acc[mt][s] = __builtin_amdgcn_mfma_f32_16x16x32_bf16(al[ks], bh, acc[mt][s], 0, 0, 0);
                    acc[mt][s] = __builtin_amdgcn_mfma_f32_16x16x32_bf16(ah[ks], bl, acc[mt][s], 0, 0, 0);
                    acc[mt][s] = __builtin_amdgcn_mfma_f32_16x16x32_bf16(ah[ks], bh, acc[mt][s], 0, 0, 0);
                }
            }
        }
        __syncthreads();
    }

    // ---- phase B: in-register masked softmax ----
    // TRUE m for acc[mt][s]: m = wc*256 + mt*32 + s*16 + fr
#pragma unroll
    for (int mt = 0; mt < 8; ++mt)
#pragma unroll
        for (int s = 0; s < 2; ++s) {
            int m = wc * 256 + mt * 32 + s * 16 + fr;
            bool keep = M2u8[m] != 0;
#pragma unroll
            for (int r = 0; r < 4; ++r)
                acc[mt][s][r] = keep ? acc[mt][s][r] : NEGC;
        }
    // row max (rows = wr*16 + q*4 + r)
    float rmax[4];
#pragma unroll
    for (int r = 0; r < 4; ++r) rmax[r] = NEGC;
#pragma unroll
    for (int mt = 0; mt < 8; ++mt)
#pragma unroll
        for (int s = 0; s < 2; ++s)
#pragma unroll
            for (int r = 0; r < 4; ++r) rmax[r] = fmaxf(rmax[r], acc[mt][s][r]);
#pragma unroll
    for (int off = 1; off < 16; off <<= 1)
#pragma unroll
        for (int r = 0; r < 4; ++r) rmax[r] = fmaxf(rmax[r], __shfl_xor(rmax[r], off));
    if (fr == 0) {
#pragma unroll
        for (int r = 0; r < 4; ++r) REDm[wc * 32 + wr * 16 + q * 4 + r] = rmax[r];
    }
    __syncthreads();
    float RM[4];
#pragma unroll
    for (int r = 0; r < 4; ++r) {
        int rl = wr * 16 + q * 4 + r;
        RM[r] = fmaxf(REDm[rl], REDm[32 + rl]);
    }
    if (t < 32) {  // a1 logits: rmax + (1-m1)*NEG
        float v = fmaxf(REDm[t], REDm[32 + t]);
        float m1v = (float)m1[b * 2048 + n0 + t];
        a1log[b * 2048 + n0 + t] = v + (1.0f - m1v) * NEGC;
    }
    // exp & sum (masked entries: exp(NEG - RM) == 0)
    float rs[4] = {0.f, 0.f, 0.f, 0.f};
#pragma unroll
    for (int mt = 0; mt < 8; ++mt)
#pragma unroll
        for (int s = 0; s < 2; ++s)
#pragma unroll
            for (int r = 0; r < 4; ++r) {
                float e = __expf(acc[mt][s][r] - RM[r]);
                acc[mt][s][r] = e;
                rs[r] += e;
            }
#pragma unroll
    for (int off = 1; off < 16; off <<= 1)
#pragma unroll
        for (int r = 0; r < 4; ++r) rs[r] += __shfl_xor(rs[r], off);
    if (fr == 0) {
#pragma unroll
        for (int r = 0; r < 4; ++r) REDs[wc * 32 + wr * 16 + q * 4 + r] = rs[r];
    }
    __syncthreads();
    float rinv[4];
#pragma unroll
    for (int r = 0; r < 4; ++r) {
        int rl = wr * 16 + q * 4 + r;
        rinv[r] = 1.0f / (REDs[rl] + REDs[32 + rl]);
    }
    // write a2 (global f32 + LDS bf16 for PV) at TRUE m
#pragma unroll
    for (int mt = 0; mt < 8; ++mt)
#pragma unroll
        for (int s = 0; s < 2; ++s) {
            int m = wc * 256 + mt * 32 + s * 16 + fr;
#pragma unroll
            for (int r = 0; r < 4; ++r) {
                int rl = wr * 16 + q * 4 + r;
                float v = acc[mt][s][r] * rinv[r];
                a2out[(size_t)(b * 2048 + n0 + rl) * 512 + m] = v;
                int off = (rl * 1024 + m * 2) ^ ((rl & 7) << 4);
                *(unsigned short*)(smem + off) = f2bf(v);
            }
        }

    // ---- phase C: out0 = a2 . seq2 (bf16 MFMA; V^T tiles from g_VT) ----
    f32x4 oacc[4];
#pragma unroll
    for (int c = 0; c < 4; ++c) oacc[c] = (f32x4){0.f, 0.f, 0.f, 0.f};

#pragma unroll
    for (int mt = 0; mt < 8; ++mt) {
        {   // stage T[128][64] from VT: wave w covers d rows [w*32, w*32+32)
            char* dstb = smem + TBASE + w * 4096;
#pragma unroll
            for (int i = 0; i < 4; ++i) {
                int d = w * 32 + i * 8 + (lane >> 3);
                int cb = (lane & 7) * 16;
                size_t so = (size_t)(b * 128 + d) * 1024 + mt * 128 + (cb ^ ((d & 7) << 4));
                gl_lds16((const char*)g_VT + so, dstb + i * 1024);
            }
        }
        __syncthreads();
        {
            int arow = wr * 16 + fr;
            int asw = (fr & 7) << 4;
#pragma unroll
            for (int ks = 0; ks < 2; ++ks) {
                int aoff = (arow * 1024 + mt * 128 + ks * 64 + q * 16) ^ asw;
                bf16x8 pa = *(const bf16x8*)(smem + aoff);
#pragma unroll
                for (int c = 0; c < 4; ++c) {
                    int d = wc * 64 + c * 16 + fr;
                    int boff = (d * 128 + ks * 64 + q * 16) ^ ((d & 7) << 4);
                    bf16x8 bv = *(const bf16x8*)(smem + TBASE + boff);
                    oacc[c] = __builtin_amdgcn_mfma_f32_16x16x32_bf16(pa, bv, oacc[c], 0, 0, 0);
                }
            }
        }
        __syncthreads();
    }

#pragma unroll
    for (int c = 0; c < 4; ++c)
#pragma unroll
        for (int r = 0; r < 4; ++r) {
            int rl = wr * 16 + q * 4 + r;
            int d = wc * 64 + c * 16 + fr;
            out0[(size_t)(b * 2048 + n0 + rl) * 128 + d] = oacc[c][r];
        }
}

// ---- a1 softmax over n ----
__global__ __launch_bounds__(256) void k_a1(float* __restrict__ a1slot) {
    __shared__ float wred[4];
    const int b = blockIdx.x, t = threadIdx.x, lane = t & 63, w = t >> 6;

    const float4* Lp = (const float4*)(a1slot + (size_t)b * 2048);
    float4 La = Lp[t * 2], Lb = Lp[t * 2 + 1];
    float l[8] = {La.x, La.y, La.z, La.w, Lb.x, Lb.y, Lb.z, Lb.w};

    float lmax = l[0];
#pragma unroll
    for (int j = 1; j < 8; ++j) lmax = fmaxf(lmax, l[j]);
#pragma unroll
    for (int off = 1; off < 64; off <<= 1) lmax = fmaxf(lmax, __shfl_xor(lmax, off));
    if (lane == 0) wred[w] = lmax;
    __syncthreads();
    float bmax = fmaxf(fmaxf(wred[0], wred[1]), fmaxf(wred[2], wred[3]));

    float e[8]; float s = 0.f;
#pragma unroll
    for (int j = 0; j < 8; ++j) { e[j] = __expf(l[j] - bmax); s += e[j]; }
#pragma unroll
    for (int off = 1; off < 64; off <<= 1) s += __shfl_xor(s, off);
    __syncthreads();
    if (lane == 0) wred[w] = s;
    __syncthreads();
    float inv = 1.0f / (wred[0] + wred[1] + wred[2] + wred[3]);

    float4 o1{e[0] * inv, e[1] * inv, e[2] * inv, e[3] * inv};
    float4 o2v{e[4] * inv, e[5] * inv, e[6] * inv, e[7] * inv};
    ((float4*)(a1slot + (size_t)b * 2048))[t * 2] = o1;
    ((float4*)(a1slot + (size_t)b * 2048))[t * 2 + 1] = o2v;
}

// ---- partial GEMV: out2 partials over 256-row chunks ----
__global__ __launch_bounds__(256) void k_gemv(const float* __restrict__ seq1,
                                              const float* __restrict__ a1) {
    __shared__ float a1b[256];
    __shared__ float4 red[8][32];
    const int bid = blockIdx.x, b = bid >> 3, ch = bid & 7, t = threadIdx.x;
    const int n0 = ch * 256;
    if (t < 64) ((float4*)a1b)[t] = ((const float4*)(a1 + (size_t)b * 2048 + n0))[t];
    __syncthreads();
    const int d4 = t & 31, sl = t >> 5;
    float4 acc{0.f, 0.f, 0.f, 0.f};
    const float4* s1 = (const float4*)(seq1 + (size_t)(b * 2048 + n0 + sl * 32) * 128);
#pragma unroll 8
    for (int j = 0; j < 32; ++j) {
        float wv = a1b[sl * 32 + j];
        float4 v = s1[j * 32 + d4];
        acc.x += wv * v.x; acc.y += wv * v.y; acc.z += wv * v.z; acc.w += wv * v.w;
    }
    red[sl][d4] = acc;
    __syncthreads();
    if (t < 32) {
        float4 s0 = red[0][t];
#pragma unroll
        for (int c = 1; c < 8; ++c) {
            float4 v = red[c][t];
            s0.x += v.x; s0.y += v.y; s0.z += v.z; s0.w += v.w;
        }
        ((float4*)(g_part + (size_t)(b * 8 + ch) * 128))[t] = s0;
    }
}

__global__ __launch_bounds__(128) void k_final(float* __restrict__ out2) {
    const int b = blockIdx.x, t = threadIdx.x;
    float s = 0.f;
#pragma unroll
    for (int c = 0; c < 8; ++c) s += g_part[(size_t)(b * 8 + c) * 128 + t];
    out2[b * 128 + t] = s;
}

extern "C" void kernel_launch(void* const* d_in, const int* in_sizes, int n_in,
                              void* d_out, int out_size, void* d_ws, size_t ws_size,
                              hipStream_t stream) {
    const float* seq1 = (const float*)d_in[0];
    const float* seq2 = (const float*)d_in[1];
    const int*   m1   = (const int*)d_in[2];
    const int*   m2   = (const int*)d_in[3];
    (void)d_ws; (void)ws_size; (void)n_in; (void)in_sizes;

    float* out  = (float*)d_out;
    float* out0 = out;                 // [32,2048,128]
    float* a2o  = out + 8388608;       // [32,2048,512]
    float* o2   = out + 41943040;      // [32,128]
    float* a1o  = out + 41947136;      // [32,2048] (logits then final a1)

    k_prep<<<dim3(64), dim3(256), 0, stream>>>(seq2);
    bidir_main<<<dim3(2048), dim3(256), 0, stream>>>(seq1, m1, m2, out0, a2o, a1o);
    k_a1<<<dim3(32), dim3(256), 0, stream>>>(a1o);
    k_gemv<<<dim3(256), dim3(256), 0, stream>>>(seq1, a1o);
    k_final<<<dim3(32), dim3(128), 0, stream>>>(o2);
}